// Round 11
// baseline (207.420 us; speedup 1.0000x reference)
//
#include <hip/hip_runtime.h>

#define NN 100000
#define NE 3200000
#define DF 512
#define HID 16
#define NC 7
#define NBK 782          // buckets of 128 nodes
#define BCAP 6144        // per-bucket edge capacity (mean 4096, +32 sigma)
#define GEMM_BLOCKS 391  // 256 rows per block (8 waves x 32 rows)
#define NWAVE 3125       // 100000 / 32 rows per wave
#define SC_B 640         // scatter blocks
#define SEDG 5000        // edges per scatter block (640*5000 = NE exactly)

// ---------------- zero int array ----------------
__global__ void k_zero_i(int* __restrict__ p, int n) {
    int i = blockIdx.x * blockDim.x + threadIdx.x;
    if (i < n) p[i] = 0;
}

union SMem {
    float w[DF * HID];  // 32 KB, GEMM role
    struct {            // scatter role: 31.4 KB
        int stage[SEDG];
        int off[783];
        int part[512];
        int cur[782];
        int gofs[782];
    } s;
};

// ---------------- fused: bucket scatter (blocks [0,SC_B)) + thin GEMM ----------------
// GEMM: 2 rows/thread + named-register next-iter prefetch -> guaranteed 2-4
// independent loads in flight per thread; 4 W ds_reads feed 32 FMAs.
__global__ __launch_bounds__(512, 4) void k_fused(const float* __restrict__ x,
                                                  const float* __restrict__ W1,
                                                  const int* __restrict__ src,
                                                  const int* __restrict__ dst,
                                                  float* __restrict__ h1,
                                                  int* __restrict__ bcnt,
                                                  int* __restrict__ pk) {
    __shared__ SMem u;
    int tid = threadIdx.x;
    if (blockIdx.x < SC_B) {
        int* stage = u.s.stage;
        int* off   = u.s.off;
        int* part  = u.s.part;
        int* cur   = u.s.cur;
        int* gofs  = u.s.gofs;
        int e0 = blockIdx.x * SEDG;
        for (int i = tid; i < NBK; i += 512) cur[i] = 0;
        __syncthreads();
        for (int e = e0 + tid; e < e0 + SEDG; e += 512) atomicAdd(&cur[dst[e] >> 7], 1);
        __syncthreads();
        // exclusive scan cur -> off (512-thread, 2 buckets/thread), off[NBK]=SEDG
        {
            int base = tid * 2;
            int sum = 0;
#pragma unroll
            for (int j = 0; j < 2; ++j) if (base + j < NBK) sum += cur[base + j];
            part[tid] = sum;
            __syncthreads();
            for (int s2 = 1; s2 < 512; s2 <<= 1) {
                int v = (tid >= s2) ? part[tid - s2] : 0;
                __syncthreads();
                part[tid] += v;
                __syncthreads();
            }
            int run = (tid > 0) ? part[tid - 1] : 0;
#pragma unroll
            for (int j = 0; j < 2; ++j) {
                int idx = base + j;
                if (idx < NBK) { off[idx] = run; run += cur[idx]; }
            }
            if (tid == 0) off[NBK] = SEDG;
        }
        __syncthreads();
        for (int i = tid; i < NBK; i += 512) {
            int h = cur[i];
            int g = h ? atomicAdd(&bcnt[i], h) : 0;
            gofs[i] = g - off[i];
            cur[i] = off[i];
        }
        __syncthreads();
        for (int e = e0 + tid; e < e0 + SEDG; e += 512) {
            int d = dst[e];
            int pos = atomicAdd(&cur[d >> 7], 1);  // LDS returning atomic
            stage[pos] = src[e] | ((d & 127) << 17);
        }
        __syncthreads();
        for (int i = tid; i < SEDG; i += 512) {
            int lo = 0, hi = NBK;
            while (hi - lo > 1) { int mid = (lo + hi) >> 1; if (off[mid] <= i) lo = mid; else hi = mid; }
            int idx = gofs[lo] + i;
            if (idx < BCAP) pk[(size_t)lo * BCAP + idx] = stage[i];
        }
        return;
    }
    // ---- GEMM role: 8 waves x 32 rows = 256 rows/block, 2 rows/thread ----
    {
        const float4* wg = (const float4*)W1;
        float4* wl = (float4*)u.w;
#pragma unroll
        for (int i = 0; i < 4; ++i) wl[tid + 512 * i] = wg[tid + 512 * i];
    }
    __syncthreads();
    int wid = (blockIdx.x - SC_B) * 8 + (tid >> 6);
    if (wid >= NWAVE) return;
    int lane = tid & 63;
    int r = lane >> 2, cc = lane & 3;
    int row0 = wid * 32 + r;       // rows row0 and row0+16, both < NN
    const float4* xr0 = (const float4*)(x + (size_t)row0 * DF);
    const float4* xr1 = (const float4*)(x + (size_t)(row0 + 16) * DF);
    const float4* wl = (const float4*)u.w;  // float4 index: k*4 + cc
    float4 acc0 = make_float4(0.f, 0.f, 0.f, 0.f);
    float4 acc1 = make_float4(0.f, 0.f, 0.f, 0.f);
    float4 na = xr0[0], nb = xr1[0];
#pragma unroll 4
    for (int i = 0; i < 127; ++i) {
        float4 ca = na, cb = nb;
        na = xr0[i + 1];
        nb = xr1[i + 1];
        float4 w0 = wl[(4 * i + 0) * 4 + cc];
        float4 w1v = wl[(4 * i + 1) * 4 + cc];
        float4 w2 = wl[(4 * i + 2) * 4 + cc];
        float4 w3 = wl[(4 * i + 3) * 4 + cc];
        acc0.x = fmaf(ca.x, w0.x, fmaf(ca.y, w1v.x, fmaf(ca.z, w2.x, fmaf(ca.w, w3.x, acc0.x))));
        acc0.y = fmaf(ca.x, w0.y, fmaf(ca.y, w1v.y, fmaf(ca.z, w2.y, fmaf(ca.w, w3.y, acc0.y))));
        acc0.z = fmaf(ca.x, w0.z, fmaf(ca.y, w1v.z, fmaf(ca.z, w2.z, fmaf(ca.w, w3.z, acc0.z))));
        acc0.w = fmaf(ca.x, w0.w, fmaf(ca.y, w1v.w, fmaf(ca.z, w2.w, fmaf(ca.w, w3.w, acc0.w))));
        acc1.x = fmaf(cb.x, w0.x, fmaf(cb.y, w1v.x, fmaf(cb.z, w2.x, fmaf(cb.w, w3.x, acc1.x))));
        acc1.y = fmaf(cb.x, w0.y, fmaf(cb.y, w1v.y, fmaf(cb.z, w2.y, fmaf(cb.w, w3.y, acc1.y))));
        acc1.z = fmaf(cb.x, w0.z, fmaf(cb.y, w1v.z, fmaf(cb.z, w2.z, fmaf(cb.w, w3.z, acc1.z))));
        acc1.w = fmaf(cb.x, w0.w, fmaf(cb.y, w1v.w, fmaf(cb.z, w2.w, fmaf(cb.w, w3.w, acc1.w))));
    }
    {   // final iteration i = 127
        const int i = 127;
        float4 ca = na, cb = nb;
        float4 w0 = wl[(4 * i + 0) * 4 + cc];
        float4 w1v = wl[(4 * i + 1) * 4 + cc];
        float4 w2 = wl[(4 * i + 2) * 4 + cc];
        float4 w3 = wl[(4 * i + 3) * 4 + cc];
        acc0.x = fmaf(ca.x, w0.x, fmaf(ca.y, w1v.x, fmaf(ca.z, w2.x, fmaf(ca.w, w3.x, acc0.x))));
        acc0.y = fmaf(ca.x, w0.y, fmaf(ca.y, w1v.y, fmaf(ca.z, w2.y, fmaf(ca.w, w3.y, acc0.y))));
        acc0.z = fmaf(ca.x, w0.z, fmaf(ca.y, w1v.z, fmaf(ca.z, w2.z, fmaf(ca.w, w3.z, acc0.z))));
        acc0.w = fmaf(ca.x, w0.w, fmaf(ca.y, w1v.w, fmaf(ca.z, w2.w, fmaf(ca.w, w3.w, acc0.w))));
        acc1.x = fmaf(cb.x, w0.x, fmaf(cb.y, w1v.x, fmaf(cb.z, w2.x, fmaf(cb.w, w3.x, acc1.x))));
        acc1.y = fmaf(cb.x, w0.y, fmaf(cb.y, w1v.y, fmaf(cb.z, w2.y, fmaf(cb.w, w3.y, acc1.y))));
        acc1.z = fmaf(cb.x, w0.z, fmaf(cb.y, w1v.z, fmaf(cb.z, w2.z, fmaf(cb.w, w3.z, acc1.z))));
        acc1.w = fmaf(cb.x, w0.w, fmaf(cb.y, w1v.w, fmaf(cb.z, w2.w, fmaf(cb.w, w3.w, acc1.w))));
    }
    *(float4*)(h1 + (size_t)row0 * HID + cc * 4) = acc0;
    *(float4*)(h1 + (size_t)(row0 + 16) * HID + cc * 4) = acc1;
}

// ---------------- per-bucket counting sort (LDS) -> node-contiguous CSR in pk ----------------
__global__ __launch_bounds__(256) void k_sortB(const int* __restrict__ bcnt,
                                               int* __restrict__ pk,
                                               float* __restrict__ dinv,
                                               float* __restrict__ h1,
                                               int* __restrict__ ptrg,
                                               int* __restrict__ cntg) {
    __shared__ int sorted[BCAP];  // 24 KB
    __shared__ int hist[128];
    __shared__ int off[128];
    __shared__ int cur[128];
    __shared__ float dl[128];
    int b = blockIdx.x, tid = threadIdx.x;
    if (tid < 128) hist[tid] = 0;
    __syncthreads();
    int n = min(bcnt[b], BCAP);
    int* p = pk + (size_t)b * BCAP;
    for (int i = tid; i < n; i += 256) atomicAdd(&hist[p[i] >> 17], 1);
    __syncthreads();
    if (tid < 128) off[tid] = hist[tid];
    __syncthreads();
    for (int s2 = 1; s2 < 128; s2 <<= 1) {  // inclusive scan
        int u = 0;
        if (tid < 128 && tid >= s2) u = off[tid - s2];
        __syncthreads();
        if (tid < 128) off[tid] += u;
        __syncthreads();
    }
    if (tid < 128) {
        int start = off[tid] - hist[tid];  // exclusive
        cur[tid] = start;
        int node = b * 128 + tid;
        float di = rsqrtf((float)hist[tid] + 1.0f);
        dl[tid] = di;
        if (node < NN) {
            dinv[node] = di;
            ptrg[node] = b * BCAP + start;
            cntg[node] = hist[tid];
        }
    }
    __syncthreads();
    for (int i = tid; i < n; i += 256) {
        int v = p[i];
        int pos = atomicAdd(&cur[v >> 17], 1);  // LDS returning atomic
        sorted[pos] = v & 0x1FFFF;
    }
    __syncthreads();
    for (int i = tid; i < n; i += 256) p[i] = sorted[i];  // in-place write-back
    float4* hp = (float4*)(h1 + (size_t)b * 128 * HID);
    for (int i = tid; i < 512; i += 256) {
        int ln = i >> 2;
        int node = b * 128 + ln;
        if (node < NN) {
            float di = dl[ln];
            float4 v = hp[i];
            v.x *= di; v.y *= di; v.z *= di; v.w *= di;
            hp[i] = v;
        }
    }
}

// ---------------- layer-1: register aggregate + self + bias + relu + (16->7) ----------------
__global__ __launch_bounds__(256) void k_agg1(const int* __restrict__ ptrg,
                                              const int* __restrict__ cntg,
                                              const int* __restrict__ csr,
                                              const float* __restrict__ dinv,
                                              const float* __restrict__ h1s,
                                              const float* __restrict__ b1,
                                              const float* __restrict__ W2,
                                              float* __restrict__ h2s) {
    int tid = threadIdx.x;
    int ch = tid & 15;
    int d = blockIdx.x * 16 + (tid >> 4);
    if (d >= NN) return;
    int st = ptrg[d], n = cntg[d];
    float did = dinv[d];
    float a0 = 0.f, a1 = 0.f;
    int e = st, end = st + n;
    for (; e + 1 < end; e += 2) {
        int s0 = csr[e], s1 = csr[e + 1];  // broadcast in group
        a0 += h1s[(size_t)s0 * HID + ch];
        a1 += h1s[(size_t)s1 * HID + ch];
    }
    if (e < end) a0 += h1s[(size_t)csr[e] * HID + ch];
    float acc = (a0 + a1 + h1s[(size_t)d * HID + ch]) * did + b1[ch];
    float hr = fmaxf(acc, 0.f);
    float hj = 0.f;
#pragma unroll
    for (int k = 0; k < HID; ++k) {
        float hk = __shfl(hr, k, 16);
        if (ch < NC) hj = fmaf(hk, W2[k * NC + ch], hj);
    }
    if (ch < NC) h2s[(size_t)d * NC + ch] = hj * did;  // pre-scale for layer 2
}

// ---------------- layer-2: register aggregate + self + bias + log_softmax ----------------
__global__ __launch_bounds__(256) void k_agg2(const int* __restrict__ ptrg,
                                              const int* __restrict__ cntg,
                                              const int* __restrict__ csr,
                                              const float* __restrict__ dinv,
                                              const float* __restrict__ h2s,
                                              const float* __restrict__ b2,
                                              float* __restrict__ out) {
    int tid = threadIdx.x;
    int ch = tid & 7;
    int d = blockIdx.x * 32 + (tid >> 3);
    if (d >= NN) return;
    int st = ptrg[d], n = cntg[d];
    float did = dinv[d];
    float a0 = 0.f, a1 = 0.f;
    int e = st, end = st + n;
    for (; e + 1 < end; e += 2) {
        int s0 = csr[e], s1 = csr[e + 1];
        if (ch < NC) {
            a0 += h2s[(size_t)s0 * NC + ch];
            a1 += h2s[(size_t)s1 * NC + ch];
        }
    }
    if (e < end && ch < NC) a0 += h2s[(size_t)csr[e] * NC + ch];
    float o = -1e30f;
    if (ch < NC) o = (a0 + a1 + h2s[(size_t)d * NC + ch]) * did + b2[ch];
    float m = o;
#pragma unroll
    for (int offm = 1; offm < 8; offm <<= 1) m = fmaxf(m, __shfl_xor(m, offm, 8));
    float ex = (ch < NC) ? expf(o - m) : 0.f;
    float s8 = ex;
#pragma unroll
    for (int offm = 1; offm < 8; offm <<= 1) s8 += __shfl_xor(s8, offm, 8);
    if (ch < NC) out[(size_t)d * NC + ch] = o - m - logf(s8);
}

extern "C" void kernel_launch(void* const* d_in, const int* in_sizes, int n_in,
                              void* d_out, int out_size, void* d_ws, size_t ws_size,
                              hipStream_t stream) {
    const float* x  = (const float*)d_in[0];
    const int*   ei = (const int*)d_in[1];
    const float* W1 = (const float*)d_in[2];
    const float* b1 = (const float*)d_in[3];
    const float* W2 = (const float*)d_in[4];
    const float* b2 = (const float*)d_in[5];
    float* out = (float*)d_out;

    const int* src = ei;       // edge_index[0]
    const int* dst = ei + NE;  // edge_index[1]

    // ws layout: [bcnt 784 | pk NBK*BCAP | dinv NN | h1 16NN | h2 7NN | ptrg NN | cntg NN]
    int*   bcnt = (int*)d_ws;
    int*   pk   = bcnt + 784;
    float* dinv = (float*)(pk + (size_t)NBK * BCAP);
    float* h1   = dinv + NN;
    float* h2   = h1 + (size_t)HID * NN;
    int*   ptrg = (int*)(h2 + (size_t)NC * NN);
    int*   cntg = ptrg + NN;

    k_zero_i<<<4, 256, 0, stream>>>(bcnt, 784);
    k_fused <<<SC_B + GEMM_BLOCKS, 512, 0, stream>>>(x, W1, src, dst, h1, bcnt, pk);
    k_sortB <<<NBK, 256, 0, stream>>>(bcnt, pk, dinv, h1, ptrg, cntg);
    k_agg1  <<<(NN + 15) / 16, 256, 0, stream>>>(ptrg, cntg, pk, dinv, h1, b1, W2, h2);
    k_agg2  <<<(NN + 31) / 32, 256, 0, stream>>>(ptrg, cntg, pk, dinv, h2, b2, out);
}

// Round 12
// 199.381 us; speedup vs baseline: 1.0403x; 1.0403x over previous
//
#include <hip/hip_runtime.h>

#define NN 100000
#define NE 3200000
#define DF 512
#define HID 16
#define NC 7
#define NBK 782           // buckets of 128 nodes
#define BCAP 6144         // per-bucket edge capacity
#define SC_B 640          // scatter blocks
#define SEDG 5000         // edges per scatter block
#define GB 782            // gemm blocks: 128 rows each (4 waves x 32 rows)

// ---------------- zero int array ----------------
__global__ void k_zero_i(int* __restrict__ p, int n) {
    int i = blockIdx.x * blockDim.x + threadIdx.x;
    if (i < n) p[i] = 0;
}

// ---------------- bucket scatter (standalone) ----------------
__global__ __launch_bounds__(512) void k_scat(const int* __restrict__ src,
                                              const int* __restrict__ dst,
                                              int* __restrict__ bcnt,
                                              int* __restrict__ pk) {
    __shared__ int stage[SEDG];
    __shared__ int off[NBK + 1];
    __shared__ int part[512];
    __shared__ int cur[NBK];
    __shared__ int gofs[NBK];
    int tid = threadIdx.x;
    int e0 = blockIdx.x * SEDG;
    for (int i = tid; i < NBK; i += 512) cur[i] = 0;
    __syncthreads();
    for (int e = e0 + tid; e < e0 + SEDG; e += 512) atomicAdd(&cur[dst[e] >> 7], 1);
    __syncthreads();
    {
        int base = tid * 2;
        int sum = 0;
#pragma unroll
        for (int j = 0; j < 2; ++j) if (base + j < NBK) sum += cur[base + j];
        part[tid] = sum;
        __syncthreads();
        for (int s2 = 1; s2 < 512; s2 <<= 1) {
            int v = (tid >= s2) ? part[tid - s2] : 0;
            __syncthreads();
            part[tid] += v;
            __syncthreads();
        }
        int run = (tid > 0) ? part[tid - 1] : 0;
#pragma unroll
        for (int j = 0; j < 2; ++j) {
            int idx = base + j;
            if (idx < NBK) { off[idx] = run; run += cur[idx]; }
        }
        if (tid == 0) off[NBK] = SEDG;
    }
    __syncthreads();
    for (int i = tid; i < NBK; i += 512) {
        int h = cur[i];
        int g = h ? atomicAdd(&bcnt[i], h) : 0;
        gofs[i] = g - off[i];
        cur[i] = off[i];
    }
    __syncthreads();
    for (int e = e0 + tid; e < e0 + SEDG; e += 512) {
        int d = dst[e];
        int pos = atomicAdd(&cur[d >> 7], 1);  // LDS returning atomic
        stage[pos] = src[e] | ((d & 127) << 17);
    }
    __syncthreads();
    for (int i = tid; i < SEDG; i += 512) {
        int lo = 0, hi = NBK;
        while (hi - lo > 1) { int mid = (lo + hi) >> 1; if (off[mid] <= i) lo = mid; else hi = mid; }
        int idx = gofs[lo] + i;
        if (idx < BCAP) pk[(size_t)lo * BCAP + idx] = stage[i];
    }
}

// ---------------- GEMM: h1 = x @ W1, gload_lds double-buffered pipeline ----------------
// 4 waves x 32 rows = 128 rows/block. Per wave: private x double-buffer
// (2 x 4KB), K-chunks of 32 floats, 4 global_load_lds(16B) per chunk issued
// one chunk ahead, counted vmcnt(4). XOR swizzle j=k4^(r&7) on BOTH global
// source and LDS read (bank-conflict-free, rule 21). No barriers in loop.
__global__ __launch_bounds__(256) void k_gemm(const float* __restrict__ x,
                                              const float* __restrict__ W1,
                                              float* __restrict__ h1) {
    __shared__ float4 wb[2048];        // W1: [512 k][4 quads] = 32 KB
    __shared__ float4 xb[4][2][256];   // per-wave, per-half: 32 rows x 8 quads = 4 KB
    int tid = threadIdx.x;
    // stage W1 (coalesced, once)
    {
        const float4* wg = (const float4*)W1;
#pragma unroll
        for (int i = 0; i < 8; ++i) wb[tid + 256 * i] = wg[tid + 256 * i];
    }
    __syncthreads();
    int wid = tid >> 6;
    int lane = tid & 63;
    int r = lane >> 2, cc = lane & 3;            // r in [0,16), cc in [0,4)
    int row_base = blockIdx.x * 128 + wid * 32;  // wave owns rows row_base..+31
    // staging lane mapping: rl = t*8 + (lane>>3), j = lane&7, k4 = j ^ (rl&7)
    int s_rl7 = (lane >> 3) & 7;                 // (rl & 7) is t-invariant
    int s_j = lane & 7;
    int s_k4 = s_j ^ s_rl7;
    // per-lane global source column offset (floats) within a chunk
    // full addr: x + row*DF + c*32 + s_k4*4
    long srow0 = row_base + (lane >> 3);         // row for t=0; +8 per t
#define STAGE(hb, c)                                                            \
    {                                                                           \
        _Pragma("unroll")                                                       \
        for (int t = 0; t < 4; ++t) {                                           \
            long rr = srow0 + t * 8;                                            \
            if (rr >= NN) rr = NN - 1;                                          \
            const float* gsrc = x + rr * DF + (c) * 32 + s_k4 * 4;              \
            float4* ldst = &xb[wid][hb][t * 64];                                \
            __builtin_amdgcn_global_load_lds(                                   \
                (const __attribute__((address_space(1))) void*)gsrc,            \
                (__attribute__((address_space(3))) void*)ldst, 16, 0, 0);       \
        }                                                                       \
    }
    float4 acc0 = make_float4(0.f, 0.f, 0.f, 0.f);
    float4 acc1 = make_float4(0.f, 0.f, 0.f, 0.f);
    int r7 = r & 7;
    STAGE(0, 0);
    for (int c = 0; c < 16; ++c) {
        int hb = c & 1;
        if (c < 15) STAGE(hb ^ 1, c + 1);
        if (c < 15) asm volatile("s_waitcnt vmcnt(4)" ::: "memory");
        else        asm volatile("s_waitcnt vmcnt(0)" ::: "memory");
        __builtin_amdgcn_sched_barrier(0);
        const float4* xw = xb[wid][hb];
#pragma unroll
        for (int i = 0; i < 8; ++i) {  // 8 quads per chunk
            float4 xv0 = xw[r * 8 + (i ^ r7)];
            float4 xv1 = xw[(r + 16) * 8 + (i ^ r7)];
            int kq = c * 8 + i;  // global k-quad index [0,128)
            float4 w0 = wb[(4 * kq + 0) * 4 + cc];
            float4 w1v = wb[(4 * kq + 1) * 4 + cc];
            float4 w2 = wb[(4 * kq + 2) * 4 + cc];
            float4 w3 = wb[(4 * kq + 3) * 4 + cc];
            acc0.x = fmaf(xv0.x, w0.x, fmaf(xv0.y, w1v.x, fmaf(xv0.z, w2.x, fmaf(xv0.w, w3.x, acc0.x))));
            acc0.y = fmaf(xv0.x, w0.y, fmaf(xv0.y, w1v.y, fmaf(xv0.z, w2.y, fmaf(xv0.w, w3.y, acc0.y))));
            acc0.z = fmaf(xv0.x, w0.z, fmaf(xv0.y, w1v.z, fmaf(xv0.z, w2.z, fmaf(xv0.w, w3.z, acc0.z))));
            acc0.w = fmaf(xv0.x, w0.w, fmaf(xv0.y, w1v.w, fmaf(xv0.z, w2.w, fmaf(xv0.w, w3.w, acc0.w))));
            acc1.x = fmaf(xv1.x, w0.x, fmaf(xv1.y, w1v.x, fmaf(xv1.z, w2.x, fmaf(xv1.w, w3.x, acc1.x))));
            acc1.y = fmaf(xv1.x, w0.y, fmaf(xv1.y, w1v.y, fmaf(xv1.z, w2.y, fmaf(xv1.w, w3.y, acc1.y))));
            acc1.z = fmaf(xv1.x, w0.z, fmaf(xv1.y, w1v.z, fmaf(xv1.z, w2.z, fmaf(xv1.w, w3.z, acc1.z))));
            acc1.w = fmaf(xv1.x, w0.w, fmaf(xv1.y, w1v.w, fmaf(xv1.z, w2.w, fmaf(xv1.w, w3.w, acc1.w))));
        }
    }
    long row0 = row_base + r;
    long row1 = row_base + 16 + r;
    if (row0 < NN) *(float4*)(h1 + row0 * HID + cc * 4) = acc0;
    if (row1 < NN) *(float4*)(h1 + row1 * HID + cc * 4) = acc1;
#undef STAGE
}

// ---------------- per-bucket counting sort (LDS) -> node-contiguous CSR in pk ----------------
__global__ __launch_bounds__(256) void k_sortB(const int* __restrict__ bcnt,
                                               int* __restrict__ pk,
                                               float* __restrict__ dinv,
                                               float* __restrict__ h1,
                                               int* __restrict__ ptrg,
                                               int* __restrict__ cntg) {
    __shared__ int sorted[BCAP];  // 24 KB
    __shared__ int hist[128];
    __shared__ int off[128];
    __shared__ int cur[128];
    __shared__ float dl[128];
    int b = blockIdx.x, tid = threadIdx.x;
    if (tid < 128) hist[tid] = 0;
    __syncthreads();
    int n = min(bcnt[b], BCAP);
    int* p = pk + (size_t)b * BCAP;
    for (int i = tid; i < n; i += 256) atomicAdd(&hist[p[i] >> 17], 1);
    __syncthreads();
    if (tid < 128) off[tid] = hist[tid];
    __syncthreads();
    for (int s2 = 1; s2 < 128; s2 <<= 1) {
        int u = 0;
        if (tid < 128 && tid >= s2) u = off[tid - s2];
        __syncthreads();
        if (tid < 128) off[tid] += u;
        __syncthreads();
    }
    if (tid < 128) {
        int start = off[tid] - hist[tid];
        cur[tid] = start;
        int node = b * 128 + tid;
        float di = rsqrtf((float)hist[tid] + 1.0f);
        dl[tid] = di;
        if (node < NN) {
            dinv[node] = di;
            ptrg[node] = b * BCAP + start;
            cntg[node] = hist[tid];
        }
    }
    __syncthreads();
    for (int i = tid; i < n; i += 256) {
        int v = p[i];
        int pos = atomicAdd(&cur[v >> 17], 1);
        sorted[pos] = v & 0x1FFFF;
    }
    __syncthreads();
    for (int i = tid; i < n; i += 256) p[i] = sorted[i];
    float4* hp = (float4*)(h1 + (size_t)b * 128 * HID);
    for (int i = tid; i < 512; i += 256) {
        int ln = i >> 2;
        int node = b * 128 + ln;
        if (node < NN) {
            float di = dl[ln];
            float4 v = hp[i];
            v.x *= di; v.y *= di; v.z *= di; v.w *= di;
            hp[i] = v;
        }
    }
}

// ---------------- layer-1: register aggregate + self + bias + relu + (16->7) ----------------
__global__ __launch_bounds__(256) void k_agg1(const int* __restrict__ ptrg,
                                              const int* __restrict__ cntg,
                                              const int* __restrict__ csr,
                                              const float* __restrict__ dinv,
                                              const float* __restrict__ h1s,
                                              const float* __restrict__ b1,
                                              const float* __restrict__ W2,
                                              float* __restrict__ h2s) {
    int tid = threadIdx.x;
    int ch = tid & 15;
    int d = blockIdx.x * 16 + (tid >> 4);
    if (d >= NN) return;
    int st = ptrg[d], n = cntg[d];
    float did = dinv[d];
    float a0 = 0.f, a1 = 0.f;
    int e = st, end = st + n;
    for (; e + 1 < end; e += 2) {
        int s0 = csr[e], s1 = csr[e + 1];
        a0 += h1s[(size_t)s0 * HID + ch];
        a1 += h1s[(size_t)s1 * HID + ch];
    }
    if (e < end) a0 += h1s[(size_t)csr[e] * HID + ch];
    float acc = (a0 + a1 + h1s[(size_t)d * HID + ch]) * did + b1[ch];
    float hr = fmaxf(acc, 0.f);
    float hj = 0.f;
#pragma unroll
    for (int k = 0; k < HID; ++k) {
        float hk = __shfl(hr, k, 16);
        if (ch < NC) hj = fmaf(hk, W2[k * NC + ch], hj);
    }
    if (ch < NC) h2s[(size_t)d * NC + ch] = hj * did;
}

// ---------------- layer-2: register aggregate + self + bias + log_softmax ----------------
__global__ __launch_bounds__(256) void k_agg2(const int* __restrict__ ptrg,
                                              const int* __restrict__ cntg,
                                              const int* __restrict__ csr,
                                              const float* __restrict__ dinv,
                                              const float* __restrict__ h2s,
                                              const float* __restrict__ b2,
                                              float* __restrict__ out) {
    int tid = threadIdx.x;
    int ch = tid & 7;
    int d = blockIdx.x * 32 + (tid >> 3);
    if (d >= NN) return;
    int st = ptrg[d], n = cntg[d];
    float did = dinv[d];
    float a0 = 0.f, a1 = 0.f;
    int e = st, end = st + n;
    for (; e + 1 < end; e += 2) {
        int s0 = csr[e], s1 = csr[e + 1];
        if (ch < NC) {
            a0 += h2s[(size_t)s0 * NC + ch];
            a1 += h2s[(size_t)s1 * NC + ch];
        }
    }
    if (e < end && ch < NC) a0 += h2s[(size_t)csr[e] * NC + ch];
    float o = -1e30f;
    if (ch < NC) o = (a0 + a1 + h2s[(size_t)d * NC + ch]) * did + b2[ch];
    float m = o;
#pragma unroll
    for (int offm = 1; offm < 8; offm <<= 1) m = fmaxf(m, __shfl_xor(m, offm, 8));
    float ex = (ch < NC) ? expf(o - m) : 0.f;
    float s8 = ex;
#pragma unroll
    for (int offm = 1; offm < 8; offm <<= 1) s8 += __shfl_xor(s8, offm, 8);
    if (ch < NC) out[(size_t)d * NC + ch] = o - m - logf(s8);
}

extern "C" void kernel_launch(void* const* d_in, const int* in_sizes, int n_in,
                              void* d_out, int out_size, void* d_ws, size_t ws_size,
                              hipStream_t stream) {
    const float* x  = (const float*)d_in[0];
    const int*   ei = (const int*)d_in[1];
    const float* W1 = (const float*)d_in[2];
    const float* b1 = (const float*)d_in[3];
    const float* W2 = (const float*)d_in[4];
    const float* b2 = (const float*)d_in[5];
    float* out = (float*)d_out;

    const int* src = ei;       // edge_index[0]
    const int* dst = ei + NE;  // edge_index[1]

    // ws layout: [bcnt 784 | pk NBK*BCAP | dinv NN | h1 16NN | h2 7NN | ptrg NN | cntg NN]
    int*   bcnt = (int*)d_ws;
    int*   pk   = bcnt + 784;
    float* dinv = (float*)(pk + (size_t)NBK * BCAP);
    float* h1   = dinv + NN;
    float* h2   = h1 + (size_t)HID * NN;
    int*   ptrg = (int*)(h2 + (size_t)NC * NN);
    int*   cntg = ptrg + NN;

    k_zero_i<<<4, 256, 0, stream>>>(bcnt, 784);
    k_scat  <<<SC_B, 512, 0, stream>>>(src, dst, bcnt, pk);
    k_gemm  <<<GB, 256, 0, stream>>>(x, W1, h1);
    k_sortB <<<NBK, 256, 0, stream>>>(bcnt, pk, dinv, h1, ptrg, cntg);
    k_agg1  <<<(NN + 15) / 16, 256, 0, stream>>>(ptrg, cntg, pk, dinv, h1, b1, W2, h2);
    k_agg2  <<<(NN + 31) / 32, 256, 0, stream>>>(ptrg, cntg, pk, dinv, h2, b2, out);
}